// Round 1
// baseline (1095.650 us; speedup 1.0000x reference)
//
#include <hip/hip_runtime.h>

#define Lc    1024
#define Cc    256
#define WINc  80
#define FEATc 256
#define WPAD  84   // 84*4 = 336 B row stride, 16B-aligned for float4 LDS reads

// ---------------------------------------------------------------------------
// Precompute: G[w][w'] = sum_f Wq[w,f] * Wk[w',f]   (80x80)
//             b2[w']   = sum_f bq[f]  * Wk[w',f]    (80)
// (bq/bk row-constant terms cancel in the softmax; bk is unused entirely.)
// ---------------------------------------------------------------------------
__global__ __launch_bounds__(128) void precompute_kernel(
    const float* __restrict__ Wq, const float* __restrict__ bq,
    const float* __restrict__ Wk,
    float* __restrict__ G, float* __restrict__ b2)
{
    const int w = blockIdx.x;    // 0..80 (80 == b2 block)
    const int t = threadIdx.x;   // w'
    if (t >= WINc) return;
    if (w < WINc) {
        float acc = 0.f;
        for (int f = 0; f < FEATc; ++f)
            acc = fmaf(Wq[w * FEATc + f], Wk[t * FEATc + f], acc);
        G[w * WINc + t] = acc;
    } else {
        float acc = 0.f;
        for (int f = 0; f < FEATc; ++f)
            acc = fmaf(bq[f], Wk[t * FEATc + f], acc);
        b2[t] = acc;
    }
}

// ---------------------------------------------------------------------------
// Main kernel: one block per output position l. Thread = row c (256 threads).
//   win[c][w] = x[c, start(l)+w]
//   T[c][w']  = sum_w win[c][w] * G[w][w']        (80 regs/thread)
//   S[c][d]   = sum_w' T[c][w'] * win[d][w'] + beta[d]
//   P = softmax_d(S);  sbar[d] = mean_c P[c][d]
//   u[w] = sum_d sbar[d] * win[d][w]
//   pooled[f] = sum_w u[w]*Wv[w,f] + bv[f]
//   out[c_out, l] = sum_f pooled[f]*Wf[f,c_out] + bf[c_out]
// ---------------------------------------------------------------------------
__global__ __launch_bounds__(256) void local_attn_kernel(
    const float* __restrict__ x,
    const float* __restrict__ Wv, const float* __restrict__ bv,
    const float* __restrict__ Wf, const float* __restrict__ bf,
    const float* __restrict__ G,  const float* __restrict__ b2g,
    float* __restrict__ out)
{
    __shared__ float win[Cc][WPAD];        // 86016 B
    __shared__ float Gl[WINc * WINc];      // 25600 B
    __shared__ float b2l[WINc];
    __shared__ float beta[Cc];
    __shared__ float partial[4][Cc];
    __shared__ float sbar[Cc];
    __shared__ float ubuf[WINc];
    __shared__ float pooled[FEATc];

    const int l = blockIdx.x;
    int s = l - WINc / 2;
    s = s < 0 ? 0 : (s > (Lc - WINc) ? (Lc - WINc) : s);
    const int tid = threadIdx.x;

    // stage G, b2
    for (int i = tid; i < WINc * WINc; i += 256) Gl[i] = G[i];
    if (tid < WINc) b2l[tid] = b2g[tid];
    // stage window (coalesced within rows of 80)
    for (int i = tid; i < Cc * WINc; i += 256) {
        const int c = i / WINc;
        const int w = i - c * WINc;
        win[c][w] = x[c * Lc + s + w];
    }
    __syncthreads();

    const int c = tid;

    // ---- T[c][*] = win[c][*] @ G ;  beta[c] = win[c][*] . b2 ----
    float T[WINc];
    #pragma unroll
    for (int wp = 0; wp < WINc; ++wp) T[wp] = 0.f;
    float bsum = 0.f;
    for (int w = 0; w < WINc; ++w) {
        const float wv = win[c][w];
        bsum = fmaf(wv, b2l[w], bsum);
        const float* gr = &Gl[w * WINc];
        #pragma unroll
        for (int wp = 0; wp < WINc; ++wp)
            T[wp] = fmaf(wv, gr[wp], T[wp]);
    }
    beta[c] = bsum;
    __syncthreads();

    // ---- pass 1: online max & denom over d ----
    float m = -1e30f, Z = 0.f;
    for (int d = 0; d < Cc; ++d) {
        const float4* wrow = reinterpret_cast<const float4*>(&win[d][0]);
        float s0 = beta[d], s1 = 0.f, s2 = 0.f, s3 = 0.f;
        #pragma unroll
        for (int i = 0; i < WINc / 4; ++i) {
            const float4 wv = wrow[i];
            s0 = fmaf(T[4 * i + 0], wv.x, s0);
            s1 = fmaf(T[4 * i + 1], wv.y, s1);
            s2 = fmaf(T[4 * i + 2], wv.z, s2);
            s3 = fmaf(T[4 * i + 3], wv.w, s3);
        }
        const float sv = (s0 + s1) + (s2 + s3);
        const float mn = fmaxf(m, sv);
        Z = Z * __expf(m - mn) + __expf(sv - mn);
        m = mn;
    }
    const float rZ = 1.f / Z;

    // ---- pass 2: recompute S (bit-identical), accumulate sbar ----
    const int wave = tid >> 6, lane = tid & 63;
    for (int d = 0; d < Cc; ++d) {
        const float4* wrow = reinterpret_cast<const float4*>(&win[d][0]);
        float s0 = beta[d], s1 = 0.f, s2 = 0.f, s3 = 0.f;
        #pragma unroll
        for (int i = 0; i < WINc / 4; ++i) {
            const float4 wv = wrow[i];
            s0 = fmaf(T[4 * i + 0], wv.x, s0);
            s1 = fmaf(T[4 * i + 1], wv.y, s1);
            s2 = fmaf(T[4 * i + 2], wv.z, s2);
            s3 = fmaf(T[4 * i + 3], wv.w, s3);
        }
        const float sv = (s0 + s1) + (s2 + s3);
        float p = __expf(sv - m) * rZ;
        #pragma unroll
        for (int off = 32; off > 0; off >>= 1)
            p += __shfl_xor(p, off);
        if (lane == 0) partial[wave][d] = p;
    }
    __syncthreads();
    if (tid < Cc)
        sbar[tid] = (partial[0][tid] + partial[1][tid] +
                     partial[2][tid] + partial[3][tid]) * (1.0f / Cc);
    __syncthreads();

    // ---- u[w] = sum_d sbar[d] * win[d][w] ----
    if (tid < WINc) {
        float acc = 0.f;
        for (int d = 0; d < Cc; ++d)
            acc = fmaf(sbar[d], win[d][tid], acc);
        ubuf[tid] = acc;
    }
    __syncthreads();

    // ---- pooled[f] = u @ Wv + bv ----
    {
        float acc = bv[tid];
        for (int w = 0; w < WINc; ++w)
            acc = fmaf(ubuf[w], Wv[w * FEATc + tid], acc);
        pooled[tid] = acc;
    }
    __syncthreads();

    // ---- out[c_out, l] = pooled @ Wf + bf ----
    {
        float acc = bf[tid];
        for (int f = 0; f < FEATc; ++f)
            acc = fmaf(pooled[f], Wf[f * Cc + tid], acc);
        out[tid * Lc + l] = acc;
    }
}

// ---------------------------------------------------------------------------
extern "C" void kernel_launch(void* const* d_in, const int* in_sizes, int n_in,
                              void* d_out, int out_size, void* d_ws, size_t ws_size,
                              hipStream_t stream)
{
    const float* x  = (const float*)d_in[0];
    const float* Wq = (const float*)d_in[1];
    const float* bq = (const float*)d_in[2];
    const float* Wk = (const float*)d_in[3];
    // d_in[4] = bk — provably unused (cancels in softmax)
    const float* Wv = (const float*)d_in[5];
    const float* bv = (const float*)d_in[6];
    const float* Wf = (const float*)d_in[7];
    const float* bf = (const float*)d_in[8];
    float* out = (float*)d_out;

    float* G  = (float*)d_ws;            // 80*80 floats
    float* b2 = G + WINc * WINc;         // 80 floats

    hipLaunchKernelGGL(precompute_kernel, dim3(WINc + 1), dim3(128), 0, stream,
                       Wq, bq, Wk, G, b2);
    hipLaunchKernelGGL(local_attn_kernel, dim3(Lc), dim3(256), 0, stream,
                       x, Wv, bv, Wf, bf, G, b2, out);
}

// Round 2
// 92.344 us; speedup vs baseline: 11.8649x; 11.8649x over previous
//
#include <hip/hip_runtime.h>

#define Lc    1024
#define Cc    256
#define WINc  80
#define FEATc 256
#define RS    104          // LDS row stride in bf16 elements (208 B, 16B-aligned, bank-friendly)
#define KP    96           // K padded to 3 chunks of 32

typedef __attribute__((ext_vector_type(8))) short bf16x8;
typedef __attribute__((ext_vector_type(4))) float f32x4;

__device__ inline unsigned short f2bf(float f) {
    unsigned int u = __float_as_uint(f);
    unsigned int r = u + 0x7FFFu + ((u >> 16) & 1u);
    return (unsigned short)(r >> 16);
}
__device__ inline float bf2f(unsigned short h) {
    return __uint_as_float(((unsigned int)h) << 16);
}

// ---------------------------------------------------------------------------
// Precompute (into d_ws):
//   Gtb[t][w] = bf16( G[w][t] ),  G[w][t] = sum_f Wq[w,f]*Wk[t,f]   (80x104 bf16, k-pads zeroed)
//   b2[t]    = sum_f bq[f]*Wk[t,f]                                  (80 fp32)
// bk is provably unused (its terms are row-constant in the softmax).
// ---------------------------------------------------------------------------
__global__ __launch_bounds__(128) void precompute_kernel(
    const float* __restrict__ Wq, const float* __restrict__ bq,
    const float* __restrict__ Wk,
    unsigned short* __restrict__ Gtb, float* __restrict__ b2)
{
    const int w = blockIdx.x;
    const int t = threadIdx.x;
    if (w < WINc) {
        if (t < WINc) {
            float acc = 0.f;
            for (int f = 0; f < FEATc; ++f)
                acc = fmaf(Wq[w * FEATc + f], Wk[t * FEATc + f], acc);
            Gtb[t * RS + w] = f2bf(acc);
        }
    } else if (w == WINc) {
        if (t < WINc) {
            float acc = 0.f;
            for (int f = 0; f < FEATc; ++f)
                acc = fmaf(bq[f], Wk[t * FEATc + f], acc);
            b2[t] = acc;
        }
    } else { // zero Gtb[t][80..103]
        for (int i = t; i < WINc * (RS - WINc); i += 128) {
            const int r = i / (RS - WINc);
            const int j = i - r * (RS - WINc);
            Gtb[r * RS + WINc + j] = 0;
        }
    }
}

// ---------------------------------------------------------------------------
// Main kernel: one block (512 thr = 8 waves) per output position l.
//  winb[c][k]: bf16 window, k=0..79 = x, k=80 = beta[c] (B-side) , 81..95 = 0
//  Tb  [c][k]: bf16 T = win@G,        k=80 = 1.0        (A-side) , 81..95 = 0
//  step1 MFMA: T = win @ Gt^T ; step2 MFMA: S = T @ win^T  (bias via k=80)
//  softmax in-register -> column means -> sbar -> u -> pooled -> out
// ---------------------------------------------------------------------------
__global__ __launch_bounds__(512, 2) void local_attn_kernel(
    const float* __restrict__ x,
    const float* __restrict__ Wv, const float* __restrict__ bv,
    const float* __restrict__ Wf, const float* __restrict__ bf,
    const unsigned short* __restrict__ Gt_ws, const float* __restrict__ b2_ws,
    float* __restrict__ out)
{
    __shared__ unsigned short winb[Cc * RS];   // 53248 B
    __shared__ unsigned short Tb[Cc * RS];     // 53248 B
    __shared__ unsigned short Gtb[WINc * RS];  // 16640 B
    __shared__ float b2l[WINc];
    __shared__ float colpart[8][Cc];           // 8192 B
    __shared__ float sbar[Cc];
    __shared__ float upart[4][WINc];
    __shared__ float ubuf[WINc];
    __shared__ float ppart[2][FEATc];
    __shared__ float pooled[FEATc];
    __shared__ float opart[2][Cc];

    const int l = blockIdx.x;
    int s = l - WINc / 2;
    s = s < 0 ? 0 : (s > (Lc - WINc) ? (Lc - WINc) : s);
    const int tid = threadIdx.x;
    const int lane = tid & 63;
    const int wid = tid >> 6;

    // ---- stage ----
    for (int i = tid; i < Cc * WINc; i += 512) {
        const int c = i / WINc;
        const int w = i - c * WINc;
        winb[c * RS + w] = f2bf(x[c * Lc + s + w]);
    }
    for (int i = tid; i < Cc * (RS - WINc); i += 512) {
        const int c = i / (RS - WINc);
        const int j = i - c * (RS - WINc);
        winb[c * RS + WINc + j] = 0;
        Tb[c * RS + WINc + j] = (j == 0) ? (unsigned short)0x3F80 : (unsigned short)0;
    }
    {
        const unsigned int* gsrc = (const unsigned int*)Gt_ws;
        unsigned int* gdst = (unsigned int*)Gtb;
        for (int i = tid; i < WINc * RS / 2; i += 512) gdst[i] = gsrc[i];
    }
    if (tid < WINc) b2l[tid] = b2_ws[tid];
    __syncthreads();

    // ---- beta[d] = win[d] . b2  -> winb[d][80] ----
    if (tid < Cc) {
        float acc = 0.f;
        for (int w = 0; w < WINc; ++w)
            acc = fmaf(bf2f(winb[tid * RS + w]), b2l[w], acc);
        winb[tid * RS + WINc] = f2bf(acc);
    }
    __syncthreads();

    const int lr = lane & 15;
    const int lk = (lane >> 4) * 8;

    // ---- step 1: T = win @ G  (M=256 N=80 K=96), each wave 32 rows x 80 cols ----
    {
        const int rbase = wid * 32;
        #pragma unroll
        for (int mt = 0; mt < 2; ++mt) {
            const int arow = rbase + mt * 16 + lr;
            #pragma unroll
            for (int nt = 0; nt < 5; ++nt) {
                const int grow = nt * 16 + lr;
                f32x4 acc = {0.f, 0.f, 0.f, 0.f};
                #pragma unroll
                for (int kc = 0; kc < 3; ++kc) {
                    const int ko = kc * 32 + lk;
                    bf16x8 a = *(const bf16x8*)&winb[arow * RS + ko];
                    bf16x8 b = *(const bf16x8*)&Gtb[grow * RS + ko];
                    acc = __builtin_amdgcn_mfma_f32_16x16x32_bf16(a, b, acc, 0, 0, 0);
                }
                const int orow = rbase + mt * 16 + (lane >> 4) * 4;
                const int ocol = nt * 16 + lr;
                #pragma unroll
                for (int r = 0; r < 4; ++r)
                    Tb[(orow + r) * RS + ocol] = f2bf(acc[r]);
            }
        }
    }
    __syncthreads();

    // ---- step 2: S = T @ win^T (M=256 N=256 K=96), wave = 32 rows x 256 cols ----
    f32x4 acc0[16], acc1[16];
    {
        const f32x4 z4 = {0.f, 0.f, 0.f, 0.f};
        #pragma unroll
        for (int nt = 0; nt < 16; ++nt) { acc0[nt] = z4; acc1[nt] = z4; }
        const int rA0 = wid * 32 + lr;
        const int rA1 = rA0 + 16;
        #pragma unroll
        for (int kc = 0; kc < 3; ++kc) {
            const int ko = kc * 32 + lk;
            bf16x8 a0 = *(const bf16x8*)&Tb[rA0 * RS + ko];
            bf16x8 a1 = *(const bf16x8*)&Tb[rA1 * RS + ko];
            #pragma unroll
            for (int nt = 0; nt < 16; ++nt) {
                bf16x8 b = *(const bf16x8*)&winb[(nt * 16 + lr) * RS + ko];
                acc0[nt] = __builtin_amdgcn_mfma_f32_16x16x32_bf16(a0, b, acc0[nt], 0, 0, 0);
                acc1[nt] = __builtin_amdgcn_mfma_f32_16x16x32_bf16(a1, b, acc1[nt], 0, 0, 0);
            }
        }
    }

    // ---- softmax in-register: rows = wid*32 + mt*16 + (lane>>4)*4 + r, col = nt*16 + (lane&15)
    float rz0[4], rz1[4];
    #pragma unroll
    for (int r = 0; r < 4; ++r) {
        float m = acc0[0][r];
        #pragma unroll
        for (int nt = 1; nt < 16; ++nt) m = fmaxf(m, acc0[nt][r]);
        m = fmaxf(m, __shfl_xor(m, 1));
        m = fmaxf(m, __shfl_xor(m, 2));
        m = fmaxf(m, __shfl_xor(m, 4));
        m = fmaxf(m, __shfl_xor(m, 8));
        float z = 0.f;
        #pragma unroll
        for (int nt = 0; nt < 16; ++nt) {
            const float e = __expf(acc0[nt][r] - m);
            acc0[nt][r] = e; z += e;
        }
        z += __shfl_xor(z, 1); z += __shfl_xor(z, 2);
        z += __shfl_xor(z, 4); z += __shfl_xor(z, 8);
        rz0[r] = 1.f / z;
    }
    #pragma unroll
    for (int r = 0; r < 4; ++r) {
        float m = acc1[0][r];
        #pragma unroll
        for (int nt = 1; nt < 16; ++nt) m = fmaxf(m, acc1[nt][r]);
        m = fmaxf(m, __shfl_xor(m, 1));
        m = fmaxf(m, __shfl_xor(m, 2));
        m = fmaxf(m, __shfl_xor(m, 4));
        m = fmaxf(m, __shfl_xor(m, 8));
        float z = 0.f;
        #pragma unroll
        for (int nt = 0; nt < 16; ++nt) {
            const float e = __expf(acc1[nt][r] - m);
            acc1[nt][r] = e; z += e;
        }
        z += __shfl_xor(z, 1); z += __shfl_xor(z, 2);
        z += __shfl_xor(z, 4); z += __shfl_xor(z, 8);
        rz1[r] = 1.f / z;
    }

    // ---- column partial sums over this wave's 32 rows ----
    #pragma unroll
    for (int nt = 0; nt < 16; ++nt) {
        float v = 0.f;
        #pragma unroll
        for (int r = 0; r < 4; ++r)
            v += acc0[nt][r] * rz0[r] + acc1[nt][r] * rz1[r];
        v += __shfl_xor(v, 16);
        v += __shfl_xor(v, 32);
        if (lane < 16) colpart[wid][nt * 16 + lane] = v;
    }
    __syncthreads();

    // ---- sbar[d] = (1/C) * sum_c P[c][d] ----
    if (tid < Cc) {
        float v = 0.f;
        #pragma unroll
        for (int w8 = 0; w8 < 8; ++w8) v += colpart[w8][tid];
        sbar[tid] = v * (1.0f / Cc);
    }
    __syncthreads();

    // ---- u[w] = sum_d sbar[d]*win[d][w]  (320 threads, 4-way d split) ----
    if (tid < 320) {
        const int w = tid % WINc;
        const int part = tid / WINc;
        float a = 0.f;
        for (int d = part * 64; d < part * 64 + 64; ++d)
            a = fmaf(sbar[d], bf2f(winb[d * RS + w]), a);
        upart[part][w] = a;
    }
    __syncthreads();
    if (tid < WINc)
        ubuf[tid] = upart[0][tid] + upart[1][tid] + upart[2][tid] + upart[3][tid];
    __syncthreads();

    // ---- pooled[f] = u @ Wv + bv (2-way w split) ----
    {
        const int f = tid & 255;
        const int h = tid >> 8;
        float a = 0.f;
        for (int w = h * 40; w < h * 40 + 40; ++w)
            a = fmaf(ubuf[w], Wv[w * FEATc + f], a);
        ppart[h][f] = a;
    }
    __syncthreads();
    if (tid < FEATc) pooled[tid] = ppart[0][tid] + ppart[1][tid] + bv[tid];
    __syncthreads();

    // ---- out[c,l] = pooled @ Wf + bf (2-way f split) ----
    {
        const int co = tid & 255;
        const int h = tid >> 8;
        float a = 0.f;
        for (int f = h * 128; f < h * 128 + 128; ++f)
            a = fmaf(pooled[f], Wf[f * Cc + co], a);
        opart[h][co] = a;
    }
    __syncthreads();
    if (tid < Cc)
        out[tid * Lc + l] = opart[0][tid] + opart[1][tid] + bf[tid];
}

// ---------------------------------------------------------------------------
extern "C" void kernel_launch(void* const* d_in, const int* in_sizes, int n_in,
                              void* d_out, int out_size, void* d_ws, size_t ws_size,
                              hipStream_t stream)
{
    const float* x  = (const float*)d_in[0];
    const float* Wq = (const float*)d_in[1];
    const float* bq = (const float*)d_in[2];
    const float* Wk = (const float*)d_in[3];
    // d_in[4] = bk — unused (row-constant in softmax)
    const float* Wv = (const float*)d_in[5];
    const float* bv = (const float*)d_in[6];
    const float* Wf = (const float*)d_in[7];
    const float* bf = (const float*)d_in[8];
    float* out = (float*)d_out;

    unsigned short* Gtb = (unsigned short*)d_ws;              // 80*104 u16
    float* b2 = (float*)((char*)d_ws + WINc * RS * sizeof(unsigned short));

    hipLaunchKernelGGL(precompute_kernel, dim3(WINc + 2), dim3(128), 0, stream,
                       Wq, bq, Wk, Gtb, b2);
    hipLaunchKernelGGL(local_attn_kernel, dim3(Lc), dim3(512), 0, stream,
                       x, Wv, bv, Wf, bf, Gtb, b2, out);
}

// Round 3
// 77.791 us; speedup vs baseline: 14.0845x; 1.1871x over previous
//
#include <hip/hip_runtime.h>

#define Lc    1024
#define Cc    256
#define WINc  80
#define FEATc 256
#define RS    104   // LDS row stride (bf16 elems): 208 B, 16B-aligned, 20-bank row offset
#define KP    96    // K padded to 3 chunks of 32

typedef __attribute__((ext_vector_type(8))) short bf16x8;
typedef __attribute__((ext_vector_type(8))) unsigned short u16x8;
typedef __attribute__((ext_vector_type(4))) float f32x4;

__device__ inline unsigned short f2bf(float f) {
    unsigned int u = __float_as_uint(f);
    unsigned int r = u + 0x7FFFu + ((u >> 16) & 1u);
    return (unsigned short)(r >> 16);
}
__device__ inline float bf2f(unsigned short h) {
    return __uint_as_float(((unsigned int)h) << 16);
}

// ---------------------------------------------------------------------------
// Precompute Gtb (KP x RS bf16) into d_ws:
//   rows t=0..79 : Gtb[t][w] = G[w][t] = sum_f Wq[w,f]*Wk[t,f]   (w<80)
//   row  t=80    : Gtb[80][w] = b2[w] = sum_f bq[f]*Wk[w,f]      -> step1 emits beta
//   rows 81..95 and cols 80..103: zero (K/N padding)
// bk is provably unused (row-constant in the softmax).
// ---------------------------------------------------------------------------
__global__ __launch_bounds__(128) void precompute_kernel(
    const float* __restrict__ Wq, const float* __restrict__ bq,
    const float* __restrict__ Wk,
    unsigned short* __restrict__ Gtb)
{
    const int t = blockIdx.x;    // 0..95
    const int w = threadIdx.x;   // 0..127
    if (w >= RS) return;
    float acc = 0.f;
    if (t < WINc && w < WINc) {
        for (int f = 0; f < FEATc; ++f)
            acc = fmaf(Wq[w * FEATc + f], Wk[t * FEATc + f], acc);
    } else if (t == WINc && w < WINc) {
        for (int f = 0; f < FEATc; ++f)
            acc = fmaf(bq[f], Wk[w * FEATc + f], acc);
    }
    Gtb[t * RS + w] = f2bf(acc);
}

// ---------------------------------------------------------------------------
// Main kernel: one block (1024 thr = 16 waves) per position l.
//  step1 MFMA: T[256x96] = win @ Gt^T   (col 80 of T = beta, spilled fp32)
//  step2 MFMA: S[256x256] = T @ win^T ; bias added per-column in-register
//  softmax in-register -> column means -> sbar -> u -> pooled -> out
// ---------------------------------------------------------------------------
__global__ __launch_bounds__(1024, 4) void local_attn_kernel(
    const float* __restrict__ x,
    const float* __restrict__ Wv, const float* __restrict__ bv,
    const float* __restrict__ Wf, const float* __restrict__ bf,
    const unsigned short* __restrict__ Gt_ws,
    float* __restrict__ out)
{
    __shared__ unsigned short winb[Cc * RS];   // 53248 B
    __shared__ unsigned short Tb[Cc * RS];     // 53248 B
    __shared__ unsigned short Gtb[KP * RS];    // 19968 B
    __shared__ float sbeta[Cc];                // 1024 B
    __shared__ float scratch[16 * Cc];         // 16384 B (colpart / upart / ppart / opart)
    __shared__ float sbar[Cc];
    __shared__ float ubuf[WINc];
    __shared__ float pooled[FEATc];

    const int l = blockIdx.x;
    int s = l - WINc / 2;
    s = s < 0 ? 0 : (s > (Lc - WINc) ? (Lc - WINc) : s);
    const int tid  = threadIdx.x;
    const int lane = tid & 63;
    const int wid  = tid >> 6;           // 0..15
    const int lr   = lane & 15;
    const int lkq  = lane >> 4;          // 0..3

    // ---- stage window: 8 elems/thread/iter, packed b128 LDS writes ----
    for (int i = tid; i < Cc * WINc / 8; i += 1024) {
        const int c  = i / 10;
        const int j8 = (i - c * 10) * 8;
        const float* xp = &x[c * Lc + s + j8];
        u16x8 v;
        #pragma unroll
        for (int e = 0; e < 8; ++e) v[e] = f2bf(xp[e]);
        *(u16x8*)&winb[c * RS + j8] = v;
    }
    // zero K-pad cols 80..95 (cols 96..103 never read)
    for (int i = tid; i < Cc * 8; i += 1024) {
        const int c = i >> 3, j = i & 7;
        *(unsigned int*)&winb[c * RS + WINc + 2 * j] = 0u;
    }
    // stage Gtb
    for (int i = tid; i < KP * RS / 2; i += 1024)
        ((unsigned int*)Gtb)[i] = ((const unsigned int*)Gt_ws)[i];
    __syncthreads();

    // ---- step 1: T = win @ Gt^T (M=256 N=96 K=96); wave owns 16 rows ----
    {
        const int arow = wid * 16 + lr;
        #pragma unroll
        for (int nt = 0; nt < 6; ++nt) {
            f32x4 acc = {0.f, 0.f, 0.f, 0.f};
            #pragma unroll
            for (int kc = 0; kc < 3; ++kc) {
                const int ko = kc * 32 + lkq * 8;
                bf16x8 a = *(const bf16x8*)&winb[arow * RS + ko];
                bf16x8 b = *(const bf16x8*)&Gtb[(nt * 16 + lr) * RS + ko];
                acc = __builtin_amdgcn_mfma_f32_16x16x32_bf16(a, b, acc, 0, 0, 0);
            }
            const int orow = wid * 16 + lkq * 4;
            const int ocol = nt * 16 + lr;
            #pragma unroll
            for (int r = 0; r < 4; ++r)
                Tb[(orow + r) * RS + ocol] = f2bf(acc[r]);
            if (nt == 5 && lr == 0) {   // col 80 = beta (fp32, pre-rounding)
                #pragma unroll
                for (int r = 0; r < 4; ++r) sbeta[orow + r] = acc[r];
            }
        }
    }
    __syncthreads();

    // ---- step 2: S = T @ win^T (M=256 N=256 K=96); wave = 16 rows x 256 cols ----
    f32x4 acc0[16];
    {
        const f32x4 z4 = {0.f, 0.f, 0.f, 0.f};
        #pragma unroll
        for (int nt = 0; nt < 16; ++nt) acc0[nt] = z4;
        const int rA = wid * 16 + lr;
        bf16x8 a0[3];
        #pragma unroll
        for (int kc = 0; kc < 3; ++kc)
            a0[kc] = *(const bf16x8*)&Tb[rA * RS + kc * 32 + lkq * 8];
        #pragma unroll
        for (int nt = 0; nt < 16; ++nt) {
            #pragma unroll
            for (int kc = 0; kc < 3; ++kc) {
                bf16x8 b = *(const bf16x8*)&winb[(nt * 16 + lr) * RS + kc * 32 + lkq * 8];
                acc0[nt] = __builtin_amdgcn_mfma_f32_16x16x32_bf16(a0[kc], b, acc0[nt], 0, 0, 0);
            }
        }
    }

    // ---- add column bias beta[d] (softmax needs it before max/exp) ----
    #pragma unroll
    for (int nt = 0; nt < 16; ++nt) {
        const float sb = sbeta[nt * 16 + lr];
        #pragma unroll
        for (int r = 0; r < 4; ++r) acc0[nt][r] += sb;
    }

    // ---- softmax in-register: row = wid*16 + lkq*4 + r, col = nt*16 + lr ----
    float rz[4];
    #pragma unroll
    for (int r = 0; r < 4; ++r) {
        float m = acc0[0][r];
        #pragma unroll
        for (int nt = 1; nt < 16; ++nt) m = fmaxf(m, acc0[nt][r]);
        m = fmaxf(m, __shfl_xor(m, 1));
        m = fmaxf(m, __shfl_xor(m, 2));
        m = fmaxf(m, __shfl_xor(m, 4));
        m = fmaxf(m, __shfl_xor(m, 8));
        float z = 0.f;
        #pragma unroll
        for (int nt = 0; nt < 16; ++nt) {
            const float e = __expf(acc0[nt][r] - m);
            acc0[nt][r] = e; z += e;
        }
        z += __shfl_xor(z, 1); z += __shfl_xor(z, 2);
        z += __shfl_xor(z, 4); z += __shfl_xor(z, 8);
        rz[r] = 1.f / z;
    }

    // ---- column partials over this wave's 16 rows -> scratch[wid][col] ----
    #pragma unroll
    for (int nt = 0; nt < 16; ++nt) {
        float v = 0.f;
        #pragma unroll
        for (int r = 0; r < 4; ++r) v = fmaf(acc0[nt][r], rz[r], v);
        v += __shfl_xor(v, 16);
        v += __shfl_xor(v, 32);
        if (lane < 16) scratch[wid * Cc + nt * 16 + lane] = v;
    }
    __syncthreads();

    // ---- sbar[d] = mean_c P[c][d] ----
    if (tid < Cc) {
        float v = 0.f;
        #pragma unroll
        for (int w16 = 0; w16 < 16; ++w16) v += scratch[w16 * Cc + tid];
        sbar[tid] = v * (1.0f / Cc);
    }
    __syncthreads();

    // ---- u[w] = sum_d sbar[d]*win[d][w]  (8-way d split, 640 threads) ----
    if (tid < 8 * WINc) {
        const int w = tid % WINc;
        const int part = tid / WINc;
        float a = 0.f;
        for (int d = part * 32; d < part * 32 + 32; ++d)
            a = fmaf(sbar[d], bf2f(winb[d * RS + w]), a);
        scratch[part * WINc + w] = a;
    }
    __syncthreads();
    if (tid < WINc) {
        float v = 0.f;
        #pragma unroll
        for (int p = 0; p < 8; ++p) v += scratch[p * WINc + tid];
        ubuf[tid] = v;
    }
    __syncthreads();

    // ---- pooled[f] = u @ Wv + bv  (4-way w split) ----
    {
        const int f = tid & 255;
        const int part = tid >> 8;
        float a = 0.f;
        for (int w = part * 20; w < part * 20 + 20; ++w)
            a = fmaf(ubuf[w], Wv[w * FEATc + f], a);
        scratch[part * 256 + f] = a;
    }
    __syncthreads();
    if (tid < FEATc)
        pooled[tid] = scratch[tid] + scratch[256 + tid] +
                      scratch[512 + tid] + scratch[768 + tid] + bv[tid];
    __syncthreads();

    // ---- out[c,l] = pooled @ Wf + bf  (4-way f split) ----
    {
        const int co = tid & 255;
        const int part = tid >> 8;
        float a = 0.f;
        for (int f = part * 64; f < part * 64 + 64; ++f)
            a = fmaf(pooled[f], Wf[f * Cc + co], a);
        scratch[part * 256 + co] = a;
    }
    __syncthreads();
    if (tid < Cc)
        out[tid * Lc + l] = scratch[tid] + scratch[256 + tid] +
                            scratch[512 + tid] + scratch[768 + tid] + bf[tid];
}

// ---------------------------------------------------------------------------
extern "C" void kernel_launch(void* const* d_in, const int* in_sizes, int n_in,
                              void* d_out, int out_size, void* d_ws, size_t ws_size,
                              hipStream_t stream)
{
    const float* x  = (const float*)d_in[0];
    const float* Wq = (const float*)d_in[1];
    const float* bq = (const float*)d_in[2];
    const float* Wk = (const float*)d_in[3];
    // d_in[4] = bk — unused (row-constant in softmax)
    const float* Wv = (const float*)d_in[5];
    const float* bv = (const float*)d_in[6];
    const float* Wf = (const float*)d_in[7];
    const float* bf = (const float*)d_in[8];
    float* out = (float*)d_out;

    unsigned short* Gtb = (unsigned short*)d_ws;   // KP*RS bf16 = 19968 B

    hipLaunchKernelGGL(precompute_kernel, dim3(KP), dim3(128), 0, stream,
                       Wq, bq, Wk, Gtb);
    hipLaunchKernelGGL(local_attn_kernel, dim3(Lc), dim3(1024), 0, stream,
                       x, Wv, bv, Wf, bf, Gtb, out);
}

// Round 4
// 72.083 us; speedup vs baseline: 15.1998x; 1.0792x over previous
//
#include <hip/hip_runtime.h>

#define Lc    1024
#define Cc    256
#define WINc  80
#define SLOTS 96
#define RS    88          // LDS row stride (bf16 elems): 176 B, 16B-aligned, bank-balanced
#define L2E   1.44269504088896340736f

typedef __attribute__((ext_vector_type(8)))  short bf16x8;
typedef __attribute__((ext_vector_type(16))) float f32x16;
typedef __attribute__((ext_vector_type(4)))  unsigned int u32x4;

__device__ inline float bf2f(unsigned short h) { return __uint_as_float(((unsigned int)h) << 16); }
__device__ inline unsigned int cvt_pk_bf16(float lo, float hi) {
    unsigned int r;
    asm("v_cvt_pk_bf16_f32 %0, %1, %2" : "=v"(r) : "v"(lo), "v"(hi));
    return r;
}
__device__ inline unsigned short f2bf(float f) {
    unsigned int u = __float_as_uint(f);
    unsigned int r = u + 0x7FFFu + ((u >> 16) & 1u);
    return (unsigned short)(r >> 16);
}

// ---------------------------------------------------------------------------
// Precompute into d_ws:
//  Gt[s][w] (96x80 bf16): row s holds M[swap23(s)][w] * log2(e), where
//    M[k<80][w] = sum_f Wq[w,f]*Wk[k,f]  (Gram matrix, transposed)
//    M[80][w]   = sum_f bq[f]*Wk[w,f]    (-> beta row; bk cancels in softmax)
//    M[81..95]  = 0
//  swap23 (bits 2<->3 of s) makes step1's 32x32 MFMA C-layout coincide
//  bit-exactly with step2's A-fragment layout (no LDS/shuffle handoff).
//  WvWf[w][co] = (1/256) * sum_f Wv[w,f]*Wf[f,co]   (80x256 f32)
//  bias3[co]   = sum_f bv[f]*Wf[f,co] + bf[co]
// ---------------------------------------------------------------------------
__global__ __launch_bounds__(256) void precompute_kernel(
    const float* __restrict__ Wq, const float* __restrict__ bq,
    const float* __restrict__ Wk, const float* __restrict__ Wv,
    const float* __restrict__ bv, const float* __restrict__ Wf,
    const float* __restrict__ bf,
    unsigned short* __restrict__ Gt, float* __restrict__ WvWf,
    float* __restrict__ bias3)
{
    const int b = blockIdx.x;
    const int t = threadIdx.x;
    if (b < SLOTS) {
        if (t < WINc) {
            const int s = b;
            const int k = (s & ~12) | ((s & 4) << 1) | ((s & 8) >> 1);  // swap bits 2,3
            float acc = 0.f;
            if (k < WINc) {
                for (int f = 0; f < 256; ++f)
                    acc = fmaf(Wq[t * 256 + f], Wk[k * 256 + f], acc);
            } else if (k == WINc) {
                for (int f = 0; f < 256; ++f)
                    acc = fmaf(bq[f], Wk[t * 256 + f], acc);
            }
            Gt[s * WINc + t] = (k <= WINc) ? f2bf(acc * L2E) : (unsigned short)0;
        }
    } else if (b < SLOTS + WINc) {
        const int w = b - SLOTS;
        float acc = 0.f;
        for (int f = 0; f < 256; ++f)
            acc = fmaf(Wv[w * 256 + f], Wf[f * 256 + t], acc);
        WvWf[w * 256 + t] = acc * (1.0f / 256.0f);
    } else {
        float acc = bf[t];
        for (int f = 0; f < 256; ++f)
            acc = fmaf(bv[f], Wf[f * 256 + t], acc);
        bias3[t] = acc;
    }
}

// ---------------------------------------------------------------------------
// Main kernel: one block (512 thr = 8 waves) per position l; wave owns 32 rows.
//  step1 (32x32x16): tt[s,c] = Gt' @ win^T   -> C-layout == step2 A-frag layout
//  step2 (32x32x16): S[c,d] = T @ win^T (K=80 exact), bias from slot 80
//  softmax (no max-subtract; exp2 with log2e prebaked) -> column sums -> sbar
//  u = sbar @ win ; out = u @ WvWf + bias3
// ---------------------------------------------------------------------------
__global__ __launch_bounds__(512, 2) void local_attn_kernel(
    const float* __restrict__ x,
    const unsigned short* __restrict__ Gt_ws,
    const float* __restrict__ WvWf, const float* __restrict__ bias3,
    float* __restrict__ out)
{
    __shared__ __align__(16) unsigned short winb[Cc * RS];    // 45056 B
    __shared__ __align__(16) unsigned short Gtb[SLOTS * RS];  // 16896 B
    __shared__ float sbeta[Cc];
    __shared__ float sbarAcc[Cc];
    __shared__ float ubuf[WINc];
    __shared__ float scratch[8 * Cc];                          // 8192 B (colpart/upart/outpart)

    const int l = blockIdx.x;
    int s0 = l - WINc / 2;
    s0 = s0 < 0 ? 0 : (s0 > (Lc - WINc) ? (Lc - WINc) : s0);
    const int tid  = threadIdx.x;
    const int lane = tid & 63;
    const int wid  = tid >> 6;     // 0..7
    const int ln31 = lane & 31;
    const int hh   = lane >> 5;    // 0/1

    // ---- stage window (bank-balanced b128 writes, packed cvt_pk) ----
    for (int i = tid; i < Cc * WINc / 8; i += 512) {
        const int c  = i & 255;
        const int ch = i >> 8;     // 0..9
        const float* xp = &x[c * Lc + s0 + ch * 8];
        union { u32x4 u; bf16x8 v; } pk;
        pk.u.x = cvt_pk_bf16(xp[0], xp[1]);
        pk.u.y = cvt_pk_bf16(xp[2], xp[3]);
        pk.u.z = cvt_pk_bf16(xp[4], xp[5]);
        pk.u.w = cvt_pk_bf16(xp[6], xp[7]);
        *(bf16x8*)&winb[c * RS + ch * 8] = pk.v;
    }
    // ---- stage Gt (global 80-stride -> LDS 88-stride) ----
    for (int i = tid; i < SLOTS * WINc / 2; i += 512) {
        const int s = i / 40;
        const int j = i - s * 40;
        ((unsigned int*)Gtb)[s * (RS / 2) + j] = ((const unsigned int*)Gt_ws)[i];
    }
    __syncthreads();

    // ---- step 1: tt = Gt' @ win^T  (M=96 slots, N=32 cols/wave, K=80) ----
    f32x16 tt[3];
    {
        bf16x8 bfr[5];
        #pragma unroll
        for (int t = 0; t < 5; ++t)
            bfr[t] = *(const bf16x8*)&winb[(wid * 32 + ln31) * RS + t * 16 + hh * 8];
        #pragma unroll
        for (int mt = 0; mt < 3; ++mt) {
            f32x16 a;
            #pragma unroll
            for (int r = 0; r < 16; ++r) a[r] = 0.f;
            #pragma unroll
            for (int t = 0; t < 5; ++t) {
                bf16x8 afr = *(const bf16x8*)&Gtb[(mt * 32 + ln31) * RS + t * 16 + hh * 8];
                a = __builtin_amdgcn_mfma_f32_32x32x16_bf16(afr, bfr[t], a, 0, 0, 0);
            }
            tt[mt] = a;
        }
    }
    // beta (slot 80 = tt[2][8] on h=0 lanes), pre-scaled by log2e
    if (hh == 0) sbeta[wid * 32 + ln31] = tt[2][8];

    // ---- gather step2 A-frags straight from tt registers (static indices) ----
    bf16x8 af[5];
    #pragma unroll
    for (int t = 0; t < 5; ++t) {
        const int m = t >> 1, o = 8 * (t & 1);
        union { u32x4 u; bf16x8 v; } pk;
        pk.u.x = cvt_pk_bf16(tt[m][o + 0], tt[m][o + 1]);
        pk.u.y = cvt_pk_bf16(tt[m][o + 2], tt[m][o + 3]);
        pk.u.z = cvt_pk_bf16(tt[m][o + 4], tt[m][o + 5]);
        pk.u.w = cvt_pk_bf16(tt[m][o + 6], tt[m][o + 7]);
        af[t] = pk.v;
    }

    // ---- step 2: S = T @ win^T  (32 rows/wave x 256 cols, K=80) ----
    f32x16 acc[8];
    #pragma unroll
    for (int nt = 0; nt < 8; ++nt) {
        f32x16 a;
        #pragma unroll
        for (int r = 0; r < 16; ++r) a[r] = 0.f;
        #pragma unroll
        for (int t = 0; t < 5; ++t) {
            bf16x8 b = *(const bf16x8*)&winb[(nt * 32 + ln31) * RS + t * 16 + hh * 8];
            a = __builtin_amdgcn_mfma_f32_32x32x16_bf16(af[t], b, a, 0, 0, 0);
        }
        acc[nt] = a;
    }
    __syncthreads();   // sbeta visible to all waves

    // ---- softmax: rows c = 32*wid + (r&3)+8*(r>>2)+4*hh ; cols d = nt*32+ln31
    float zp[16];
    #pragma unroll
    for (int r = 0; r < 16; ++r) zp[r] = 0.f;
    #pragma unroll
    for (int nt = 0; nt < 8; ++nt) {
        const float sb = sbeta[nt * 32 + ln31];
        #pragma unroll
        for (int r = 0; r < 16; ++r) {
            const float e = exp2f(acc[nt][r] + sb);   // = exp(S+beta), log2e prebaked
            acc[nt][r] = e;
            zp[r] += e;
        }
    }
    #pragma unroll
    for (int r = 0; r < 16; ++r) {
        float z = zp[r];
        z += __shfl_xor(z, 1);
        z += __shfl_xor(z, 2);
        z += __shfl_xor(z, 4);
        z += __shfl_xor(z, 8);
        z += __shfl_xor(z, 16);
        zp[r] = __builtin_amdgcn_rcpf(z);
    }

    // ---- column partials over this wave's 32 rows -> scratch[wid][d] ----
    #pragma unroll
    for (int nt = 0; nt < 8; ++nt) {
        float v = 0.f;
        #pragma unroll
        for (int r = 0; r < 16; ++r) v = fmaf(acc[nt][r], zp[r], v);
        v += __shfl_xor(v, 32);
        if (lane < 32) scratch[wid * Cc + nt * 32 + ln31] = v;
    }
    __syncthreads();

    // ---- sbar[d] = sum_c P[c,d]  (1/C folded into WvWf) ----
    if (tid < Cc) {
        float v = 0.f;
        #pragma unroll
        for (int w8 = 0; w8 < 8; ++w8) v += scratch[w8 * Cc + tid];
        sbarAcc[tid] = v;
    }
    __syncthreads();

    // ---- u[w] = sum_d sbar[d]*win[d][w]  (4-way d split, 320 threads) ----
    if (tid < 4 * WINc) {
        const int w = tid % WINc;
        const int part = tid / WINc;
        const int d0 = part * 64;
        float a = 0.f;
        #pragma unroll 8
        for (int d = d0; d < d0 + 64; ++d)
            a = fmaf(sbarAcc[d], bf2f(winb[d * RS + w]), a);
        scratch[part * WINc + w] = a;
    }
    __syncthreads();
    if (tid < WINc)
        ubuf[tid] = scratch[tid] + scratch[WINc + tid] +
                    scratch[2 * WINc + tid] + scratch[3 * WINc + tid];
    __syncthreads();

    // ---- out[co,l] = u @ WvWf + bias3  (2-way w split) ----
    {
        const int co = tid & 255;
        const int part = tid >> 8;   // 0/1
        const int w0 = part * 40;
        float a = 0.f;
        #pragma unroll 8
        for (int w = w0; w < w0 + 40; ++w)
            a = fmaf(ubuf[w], WvWf[w * 256 + co], a);
        scratch[part * 256 + co] = a;
    }
    __syncthreads();
    if (tid < Cc)
        out[tid * Lc + l] = scratch[tid] + scratch[256 + tid] + bias3[tid];
}

// ---------------------------------------------------------------------------
extern "C" void kernel_launch(void* const* d_in, const int* in_sizes, int n_in,
                              void* d_out, int out_size, void* d_ws, size_t ws_size,
                              hipStream_t stream)
{
    const float* x  = (const float*)d_in[0];
    const float* Wq = (const float*)d_in[1];
    const float* bq = (const float*)d_in[2];
    const float* Wk = (const float*)d_in[3];
    // d_in[4] = bk — unused (row-constant in softmax)
    const float* Wv = (const float*)d_in[5];
    const float* bv = (const float*)d_in[6];
    const float* Wf = (const float*)d_in[7];
    const float* bf = (const float*)d_in[8];
    float* out = (float*)d_out;

    unsigned short* Gt = (unsigned short*)d_ws;                    // 96*80 u16 = 15360 B
    float* WvWf  = (float*)((char*)d_ws + SLOTS * WINc * 2);       // 80*256 f32 = 81920 B
    float* bias3 = WvWf + WINc * 256;                              // 256 f32

    hipLaunchKernelGGL(precompute_kernel, dim3(SLOTS + WINc + 1), dim3(256), 0, stream,
                       Wq, bq, Wk, Wv, bv, Wf, bf, Gt, WvWf, bias3);
    hipLaunchKernelGGL(local_attn_kernel, dim3(Lc), dim3(512), 0, stream,
                       x, Gt, WvWf, bias3, out);
}